// Round 8
// baseline (1553.697 us; speedup 1.0000x reference)
//
#include <hip/hip_runtime.h>
#include <math.h>
#include <stdint.h>

typedef _Float16 f16;
typedef _Float16 f16x8 __attribute__((ext_vector_type(8)));
typedef float f32x4 __attribute__((ext_vector_type(4)));
typedef unsigned short u16;
typedef u16 u16x8 __attribute__((ext_vector_type(8)));

#define HID 256
#define K1ACT 3202
#define NS1 101               // ceil(3202/32), padded K = 3232
#define NS2 8                 // 256/32
#define NPX 65536
#define BPX 64
#define NBLK (NPX/BPX)        // 1024 (layers 2/3)
#define NBL1 1024             // layer-1: 512 px-blocks x 2 col-halves

// ws layout (bytes)
#define OFF_W1 0
#define SZ_W1  ((size_t)NS1*32768)
#define OFF_W2 SZ_W1
#define SZ_W2  ((size_t)NS2*32768)
#define OFF_W3 (OFF_W2+SZ_W2)
#define OFF_H  ((size_t)4194304)

__device__ inline void split2(float v, u16& h, u16& l){
  f16 hv = (f16)v;
  f16 lv = (f16)(v - (float)hv);
  h = __builtin_bit_cast(u16, hv);
  l = __builtin_bit_cast(u16, lv);
}

// Pre-split W (fp32 [K][256]) into fp16 hi/lo MFMA-fragment units (proven r2 layout):
//   unit(s, w, nf, split, lane): 8 f16, j -> W[s*32 + (lane>>4)*8 + j][w*64 + nf*16 + (lane&15)]
//   unit offset = (((s*4 + w)*4 + nf)*2 + split)*64 + lane ; per-s slab = 32 KB contiguous;
//   col-half ch of slab s = [s*32768 + ch*16384, +16 KB) — linear.
__global__ void prep_w(const float* __restrict__ W, int Kact, int nStages,
                       u16* __restrict__ outp){
  int t = blockIdx.x*256 + threadIdx.x;
  if (t >= nStages*1024) return;
  int s = t >> 10, r = t & 1023;
  int w = r >> 8, nf = (r >> 6) & 3, l = r & 63;
  int col = w*64 + nf*16 + (l & 15);
  int kb  = s*32 + (l >> 4)*8;
  u16x8 hv, lv;
  #pragma unroll
  for (int j = 0; j < 8; ++j){
    int k = kb + j;
    float v = (k < Kact) ? W[(size_t)k*HID + col] : 0.f;
    u16 h, lo; split2(v, h, lo);
    hv[j] = h; lv[j] = lo;
  }
  size_t U0 = ((((size_t)s*4 + w)*4 + nf)*2 + 0)*64 + l;
  *(u16x8*)(outp + U0*8)      = hv;
  *(u16x8*)(outp + (U0+64)*8) = lv;
}

// ---------------------------------------------------------------------------
// Layer-1, m97 regime: 128px x 128col per block, 256 thr = 4 waves
// (wave = 64px x 64col, acc 4x4, 48 MFMA/step), BK=32, SINGLE-buffered
// 32 KB LDS, 2 barriers/K-step, 3 blocks/CU co-resident (launch_bounds 256,3)
// -> inter-block overlap hides barrier drains (m114 mechanism).
// ---------------------------------------------------------------------------
__global__ __launch_bounds__(256, 3)
void gemm_l1(const float* __restrict__ xi, const u16* __restrict__ Wp,
             const float* __restrict__ bias, uint32_t* __restrict__ hout, int nt)
{
  __shared__ __align__(16) u16 Ab[8192];   // 16 KB: [mfb(8)][split(2)][unit(64)][8]
  __shared__ __align__(16) u16 Bb[8192];   // 16 KB: [(wn*4+nf)(8)][split(2)][unit(64)][8]

  const int tid  = threadIdx.x;
  const int lane = tid & 63;
  const int wv   = tid >> 6;            // 0..3
  const int wm   = wv >> 1, wn = wv & 1;

  int bid = blockIdx.x;
  bid = (bid & 7)*(NBL1/8) + (bid >> 3);   // XCD-chunked swizzle (1024%8==0)
  const int pxb = (bid >> 1) << 7;      // 128-px block (half an image row)
  const int ch  = bid & 1;              // col-half (128 cols)
  const int y   = pxb >> 8;
  const int x0  = pxb & 255;            // 0 or 128

  const int pxl  = tid & 127;           // thread's px within tile
  const int oct0 = tid >> 7;            // first k-octet (0/1); also handles oct0+2

  const float gy = -1.f + (2.f/255.f)*(float)y;
  const float gx = -1.f + (2.f/255.f)*(float)(x0 + pxl);

  float fa[16];                          // A prefetch: 2 units x 8 k-values
  f32x4 acc[4][4];
  #pragma unroll
  for (int a=0;a<4;a++)
    #pragma unroll
    for (int b=0;b<4;b++) acc[a][b] = f32x4{0.f,0.f,0.f,0.f};

#define L1_ALOAD(S) do{ \
  _Pragma("unroll") \
  for (int u=0;u<2;++u){ \
    const int oc = oct0 + u*2; \
    _Pragma("unroll") \
    for (int j=0;j<8;++j){ \
      int k = (S)*32 + oc*8 + j; \
      float v = 0.f; \
      if (k < 3200){ \
        int c = k/25, rr = k - 25*c; \
        int dy = rr/5, dx = rr - dy*5; \
        int yy = y + dy - 2; \
        int xx = x0 + pxl + dx - 2; \
        if ((unsigned)yy < 256u && (unsigned)xx < 256u) \
          v = xi[((size_t)c<<16) + ((size_t)yy<<8) + xx]; \
      } else if (k == 3200) v = gy; \
      else if (k == 3201) v = gx; \
      fa[u*8+j] = v; \
    } \
  }}while(0)

#define L1_AWRITE() do{ \
  _Pragma("unroll") \
  for (int u=0;u<2;++u){ \
    u16x8 hv, lv; \
    _Pragma("unroll") \
    for (int j=0;j<8;++j){ u16 h,l; split2(fa[u*8+j],h,l); hv[j]=h; lv[j]=l; } \
    const int mfb = pxl >> 4; \
    const int un  = (oct0 + u*2)*16 + (pxl & 15); \
    *(u16x8*)(&Ab[(size_t)(mfb*2+0)*512 + un*8]) = hv; \
    *(u16x8*)(&Ab[(size_t)(mfb*2+1)*512 + un*8]) = lv; \
  }}while(0)

#define L1_BSTAGE(S) do{ \
  const char* _s = (const char*)Wp + (size_t)(S)*32768 + (size_t)ch*16384 + tid*16; \
  char* _d = (char*)&Bb[0] + tid*16; \
  _Pragma("unroll") \
  for (int i=0;i<4;++i) \
    __builtin_amdgcn_global_load_lds( \
      (const __attribute__((address_space(1))) uint32_t*)(_s + i*4096), \
      (__attribute__((address_space(3))) uint32_t*)(_d + i*4096), 16, 0, 0); \
 }while(0)

  L1_ALOAD(0);
  for (int t = 0; t < nt; ++t){
    L1_AWRITE();               // consumes fa(t) (vmcnt wait inserted here)
    L1_BSTAGE(t);              // 4 linear global_load_lds -> Bb
    __syncthreads();           // barrier 1: A ds_writes + B DMA visible
    if (t+1 < nt) L1_ALOAD(t+1);   // issue next A loads; MFMA section covers

    f16x8 ah[4], al[4], bh[4], bl[4];
    #pragma unroll
    for (int mf=0;mf<4;++mf){
      ah[mf] = *(const f16x8*)(&Ab[(size_t)((wm*4+mf)*2+0)*512 + lane*8]);
      al[mf] = *(const f16x8*)(&Ab[(size_t)((wm*4+mf)*2+1)*512 + lane*8]);
    }
    #pragma unroll
    for (int nf=0;nf<4;++nf){
      bh[nf] = *(const f16x8*)(&Bb[(size_t)((wn*4+nf)*2+0)*512 + lane*8]);
      bl[nf] = *(const f16x8*)(&Bb[(size_t)((wn*4+nf)*2+1)*512 + lane*8]);
    }
    __builtin_amdgcn_s_setprio(1);
    #pragma unroll
    for (int nf=0;nf<4;++nf){
      #pragma unroll
      for (int mf=0;mf<4;++mf){
        acc[mf][nf] = __builtin_amdgcn_mfma_f32_16x16x32_f16(ah[mf], bh[nf], acc[mf][nf], 0,0,0);
        acc[mf][nf] = __builtin_amdgcn_mfma_f32_16x16x32_f16(al[mf], bh[nf], acc[mf][nf], 0,0,0);
        acc[mf][nf] = __builtin_amdgcn_mfma_f32_16x16x32_f16(ah[mf], bl[nf], acc[mf][nf], 0,0,0);
      }
    }
    __builtin_amdgcn_s_setprio(0);
    __syncthreads();           // barrier 2: LDS consumed, next step may overwrite
  }

  // epilogue: h = sin(30 z) -> packed hi|lo u32, [px][ch]
  float bcol[4];
  #pragma unroll
  for (int nf=0;nf<4;++nf) bcol[nf] = bias[ch*128 + wn*64 + nf*16 + (lane&15)];
  #pragma unroll
  for (int mf=0;mf<4;++mf)
    #pragma unroll
    for (int nf=0;nf<4;++nf)
      #pragma unroll
      for (int j=0;j<4;++j){
        float z = acc[mf][nf][j] + bcol[nf];
        float h = sinf(30.f*z);
        u16 hh,ll; split2(h,hh,ll);
        int row = wm*64 + mf*16 + (lane>>4)*4 + j;
        int col = ch*128 + wn*64 + nf*16 + (lane&15);
        hout[(size_t)(pxb+row)*HID + col] = (uint32_t)hh | ((uint32_t)ll<<16);
      }
#undef L1_ALOAD
#undef L1_AWRITE
#undef L1_BSTAGE
}

// ---------------------------------------------------------------------------
// Layers 2/3(+4 tail): unchanged r5/r7 structure (64px x 256col, 4 waves, dbuf).
// MODE 1: A = h; MODE 2: A = h + fused layer-4 tail.
// ---------------------------------------------------------------------------
template<int MODE>
__global__ __launch_bounds__(256, 2)
void gemm_layer(const uint32_t* __restrict__ hin,
                const u16* __restrict__ Wp, const float* __restrict__ bias,
                uint32_t* __restrict__ hout, const float* __restrict__ W4,
                const float* __restrict__ b4, float* __restrict__ out, int nt)
{
  __shared__ __align__(16) u16 Ab[2][4096];   // 8 KB per buf
  __shared__ __align__(16) u16 Bb[2][16384];  // 32 KB per buf

  const int tid  = threadIdx.x;
  const int lane = tid & 63;
  const int wv   = tid >> 6;

  int bid = blockIdx.x;
  bid = (bid & 7)*(NBLK/8) + (bid >> 3);   // XCD-chunked swizzle (1024%8==0)
  const int pxb = bid * BPX;

  f32x4 acc[4][4];
  #pragma unroll
  for (int a=0;a<4;a++)
    #pragma unroll
    for (int b=0;b<4;b++) acc[a][b] = f32x4{0.f,0.f,0.f,0.f};

  uint32_t ua[8];

#define A_LOAD(S) do { \
    const uint32_t* hp = hin + (size_t)(pxb + lane)*HID + (S)*32 + wv*8; \
    uint4 a0 = *(const uint4*)hp; \
    uint4 a1 = *(const uint4*)(hp+4); \
    ua[0]=a0.x; ua[1]=a0.y; ua[2]=a0.z; ua[3]=a0.w; \
    ua[4]=a1.x; ua[5]=a1.y; ua[6]=a1.z; ua[7]=a1.w; \
  } while(0)

#define A_WRITE(BUF) do { \
    u16x8 hv, lv; \
    _Pragma("unroll") \
    for (int j=0;j<8;++j){ hv[j]=(u16)(ua[j]&0xffffu); lv[j]=(u16)(ua[j]>>16); } \
    int ub = ((lane>>4)*2)*64 + wv*16 + (lane&15); \
    *(u16x8*)(&Ab[BUF][(size_t)ub*8])      = hv; \
    *(u16x8*)(&Ab[BUF][(size_t)(ub+64)*8]) = lv; \
  } while(0)

#define B_STAGE(S, BUF) do { \
    const char* _src = (const char*)Wp + (size_t)(S)*32768 + wv*8192 + lane*16; \
    char* _dst = (char*)&Bb[BUF][0] + wv*8192; \
    _Pragma("unroll") \
    for (int i=0;i<8;++i) \
      __builtin_amdgcn_global_load_lds( \
        (const __attribute__((address_space(1))) uint32_t*)(_src + i*1024), \
        (__attribute__((address_space(3))) uint32_t*)(_dst + i*1024), 16, 0, 0); \
  } while(0)

  A_LOAD(0);
  B_STAGE(0, 0);
  A_WRITE(0);
  __syncthreads();

  int cur = 0;
  for (int t = 0; t < nt; ++t){
    const int nxt = cur ^ 1;
    if (t+1 < nt){
      A_LOAD(t+1);
      B_STAGE(t+1, nxt);
    }
    f16x8 ahf[4], alf[4];
    #pragma unroll
    for (int mf=0;mf<4;++mf){
      ahf[mf] = *(const f16x8*)(&Ab[cur][((size_t)((mf*2+0)*64 + lane))*8]);
      alf[mf] = *(const f16x8*)(&Ab[cur][((size_t)((mf*2+1)*64 + lane))*8]);
    }
    __builtin_amdgcn_s_setprio(1);
    #pragma unroll
    for (int nf=0;nf<4;++nf){
      f16x8 bh = *(const f16x8*)(&Bb[cur][((size_t)(((wv*4+nf)*2+0)*64 + lane))*8]);
      f16x8 bl = *(const f16x8*)(&Bb[cur][((size_t)(((wv*4+nf)*2+1)*64 + lane))*8]);
      #pragma unroll
      for (int mf=0;mf<4;++mf){
        acc[mf][nf] = __builtin_amdgcn_mfma_f32_16x16x32_f16(ahf[mf], bh, acc[mf][nf], 0,0,0);
        acc[mf][nf] = __builtin_amdgcn_mfma_f32_16x16x32_f16(alf[mf], bh, acc[mf][nf], 0,0,0);
        acc[mf][nf] = __builtin_amdgcn_mfma_f32_16x16x32_f16(ahf[mf], bl, acc[mf][nf], 0,0,0);
      }
    }
    __builtin_amdgcn_s_setprio(0);
    if (t+1 < nt) A_WRITE(nxt);
    __syncthreads();
    cur = nxt;
  }

  float bcol[4];
  #pragma unroll
  for (int nf=0;nf<4;++nf) bcol[nf] = bias[wv*64 + nf*16 + (lane&15)];

  if (MODE != 2){
    #pragma unroll
    for (int mf=0;mf<4;++mf)
      #pragma unroll
      for (int nf=0;nf<4;++nf)
        #pragma unroll
        for (int j=0;j<4;++j){
          float z = acc[mf][nf][j] + bcol[nf];
          float h = sinf(30.f*z);
          u16 hh,ll; split2(h,hh,ll);
          int row = mf*16 + (lane>>4)*4 + j;
          int col = wv*64 + nf*16 + (lane&15);
          hout[(size_t)(pxb+row)*HID + col] = (uint32_t)hh | ((uint32_t)ll<<16);
        }
  } else {
    float (*red)[64][3] = (float(*)[64][3])(void*)&Ab[0][0];
    float w4v[4][3];
    #pragma unroll
    for (int nf=0;nf<4;++nf){
      int col = wv*64 + nf*16 + (lane&15);
      w4v[nf][0]=W4[col*3+0]; w4v[nf][1]=W4[col*3+1]; w4v[nf][2]=W4[col*3+2];
    }
    #pragma unroll
    for (int mf=0;mf<4;++mf)
      #pragma unroll
      for (int j=0;j<4;++j){
        float s0=0.f,s1=0.f,s2=0.f;
        #pragma unroll
        for (int nf=0;nf<4;++nf){
          float h = sinf(30.f*(acc[mf][nf][j] + bcol[nf]));
          s0 += h*w4v[nf][0]; s1 += h*w4v[nf][1]; s2 += h*w4v[nf][2];
        }
        #pragma unroll
        for (int m=1;m<16;m<<=1){
          s0 += __shfl_xor(s0, m);
          s1 += __shfl_xor(s1, m);
          s2 += __shfl_xor(s2, m);
        }
        if ((lane & 15) == 0){
          int row = mf*16 + (lane>>4)*4 + j;
          red[wv][row][0]=s0; red[wv][row][1]=s1; red[wv][row][2]=s2;
        }
      }
    __syncthreads();
    if (tid < 192){
      int px = tid & 63, c = tid >> 6;
      float v = red[0][px][c]+red[1][px][c]+red[2][px][c]+red[3][px][c] + b4[c];
      out[(size_t)c*NPX + pxb + px] = v;
    }
  }
#undef A_LOAD
#undef A_WRITE
#undef B_STAGE
}

// ---------------------------------------------------------------------------
extern "C" void kernel_launch(void* const* d_in, const int* in_sizes, int n_in,
                              void* d_out, int out_size, void* d_ws, size_t ws_size,
                              hipStream_t stream) {
  const float* xi = (const float*)d_in[0];
  const float* W1 = (const float*)d_in[1];
  const float* b1 = (const float*)d_in[2];
  const float* W2 = (const float*)d_in[3];
  const float* b2 = (const float*)d_in[4];
  const float* W3 = (const float*)d_in[5];
  const float* b3 = (const float*)d_in[6];
  const float* W4 = (const float*)d_in[7];
  const float* b4 = (const float*)d_in[8];
  float* out = (float*)d_out;

  char* ws = (char*)d_ws;
  u16* W1p = (u16*)(ws + OFF_W1);
  u16* W2p = (u16*)(ws + OFF_W2);
  u16* W3p = (u16*)(ws + OFF_W3);
  uint32_t* h = (uint32_t*)(ws + OFF_H);

  prep_w<<<NS1*4, 256, 0, stream>>>(W1, K1ACT, NS1, W1p);
  prep_w<<<NS2*4, 256, 0, stream>>>(W2, HID, NS2, W2p);
  prep_w<<<NS2*4, 256, 0, stream>>>(W3, HID, NS2, W3p);

  gemm_l1<<<NBL1, 256, 0, stream>>>(xi, W1p, b1, h, NS1);

  dim3 grid(NBLK), block(256);
  gemm_layer<1><<<grid, block, 0, stream>>>(h, W2p, b2, h,
                                            nullptr, nullptr, nullptr, NS2);
  gemm_layer<2><<<grid, block, 0, stream>>>(h, W3p, b3, nullptr,
                                            W4, b4, out, NS2);
}